// Round 7
// baseline (294.289 us; speedup 1.0000x reference)
//
#include <hip/hip_runtime.h>
#include <hip/hip_bf16.h>
#include <stdint.h>

// Problem constants (fixed by the reference)
#define B_    4
#define N_    2048
#define DIM_  1024
#define H_    8
#define HD_   128
#define MTOK  (B_ * N_)          // 8192 tokens
#define SCALE_  0.08838834764831845f   // HD^-0.5
#define LOG2E_  1.4426950408889634f
#define QSCALE_ (SCALE_ * LOG2E_)      // folded into Q projection epilogue

typedef unsigned short u16;
typedef __attribute__((ext_vector_type(4)))  float f32x4;
typedef __attribute__((ext_vector_type(16))) float f32x16;
typedef __attribute__((ext_vector_type(8)))  short s16x8;   // 8 bf16 — MFMA A/B frag
typedef __attribute__((ext_vector_type(8)))  u16  u16x8;
typedef __attribute__((ext_vector_type(4)))  u16  u16x4;
typedef __attribute__((ext_vector_type(4)))  unsigned u32x4;

__device__ __forceinline__ u16 f2bf(float f) {
    uint32_t i = __builtin_bit_cast(uint32_t, f);
    return (u16)((i + 0x7FFFu + ((i >> 16) & 1u)) >> 16);   // RNE
}
// v_cvt_pk_bf16_f32: packs (a,b) -> u32 [b_bf16 | a_bf16] (a in low 16), RNE
__device__ __forceinline__ unsigned pk_bf16(float a, float b) {
    unsigned r;
    asm("v_cvt_pk_bf16_f32 %0, %1, %2" : "=v"(r) : "v"(a), "v"(b));
    return r;
}
// v_permlane32_swap_b32: a' = {a.lo32lanes, b.lo32lanes}, b' = {a.hi, b.hi}
__device__ __forceinline__ void pl32_swap(unsigned &a, unsigned &b) {
    asm volatile("v_permlane32_swap_b32 %0, %1" : "+v"(a), "+v"(b));
}
// direct global->LDS, 16B per lane; LDS dest = wave-uniform base + lane*16
__device__ __forceinline__ void gl_lds16(const u16* g, u16* l) {
    __builtin_amdgcn_global_load_lds((const __attribute__((address_space(1))) void*)g,
                                     (__attribute__((address_space(3))) void*)l,
                                     16, 0, 0);
}

// ---------------------------------------------------------------- cvt f32->bf16
__global__ __launch_bounds__(256) void cvt_f32_bf16(const float* __restrict__ src,
                                                    u16* __restrict__ dst, int n) {
    int i = (blockIdx.x * 256 + threadIdx.x) * 4;
    int stride = gridDim.x * 256 * 4;
    for (; i < n; i += stride) {
        float4 v = *(const float4*)(src + i);
        u16x4 o;
        o.x = f2bf(v.x); o.y = f2bf(v.y); o.z = f2bf(v.z); o.w = f2bf(v.w);
        *(u16x4*)(dst + i) = o;
    }
}

// ---------------------------------------------------------------- weight cvt (4 tensors, one launch)
__global__ __launch_bounds__(256) void cvt_w4(const float* __restrict__ s0,
                                              const float* __restrict__ s1,
                                              const float* __restrict__ s2,
                                              const float* __restrict__ s3,
                                              u16* __restrict__ dst) {
    const float* s = blockIdx.y == 0 ? s0 : blockIdx.y == 1 ? s1 : blockIdx.y == 2 ? s2 : s3;
    u16* d = dst + (size_t)blockIdx.y * (DIM_ * DIM_);
    int i = (blockIdx.x * 256 + threadIdx.x) * 8;          // grid.x=512 covers 1M elems
    float4 a = *(const float4*)(s + i);
    float4 b = *(const float4*)(s + i + 4);
    u32x4 w = {pk_bf16(a.x, a.y), pk_bf16(a.z, a.w), pk_bf16(b.x, b.y), pk_bf16(b.z, b.w)};
    *(u16x8*)(d + i) = __builtin_bit_cast(u16x8, w);
}

// ---------------------------------------------------------------- trans transpose (f32, per-batch)
// out[b][c][r] = in[b][r][c]; float4 on both global sides, scalar LDS ([64][65] = 2-way free)
__global__ __launch_bounds__(256) void transpose_f32(const float* __restrict__ in,
                                                     float* __restrict__ out) {
    __shared__ float t[64][65];
    const int r0 = blockIdx.y * 64, c0 = blockIdx.x * 64;
    const float* ib = in + (size_t)blockIdx.z * N_ * N_;
    float* ob = out + (size_t)blockIdx.z * N_ * N_;
    const int lr = threadIdx.x >> 4;      // 0..15
    const int lc = threadIdx.x & 15;      // 0..15 (x4 cols)
    #pragma unroll
    for (int i = 0; i < 4; i++) {
        int row = i * 16 + lr;
        float4 v = *(const float4*)(ib + (size_t)(r0 + row) * N_ + c0 + lc * 4);
        t[row][lc * 4 + 0] = v.x; t[row][lc * 4 + 1] = v.y;
        t[row][lc * 4 + 2] = v.z; t[row][lc * 4 + 3] = v.w;
    }
    __syncthreads();
    #pragma unroll
    for (int i = 0; i < 4; i++) {
        int row = i * 16 + lr;
        float4 w;
        w.x = t[lc * 4 + 0][row]; w.y = t[lc * 4 + 1][row];
        w.z = t[lc * 4 + 2][row]; w.w = t[lc * 4 + 3][row];
        *(float4*)(ob + (size_t)(c0 + row) * N_ + r0 + lc * 4) = w;
    }
}

// ---------------------------------------------------------------- GEMM C = A @ Bt^T  (R3-proven + T1)
// A [M,K] bf16 row-major; Bt [NN,K] bf16 row-major; both gl_lds staged (pre-swizzled source).
// MODE 0: bf16 head-split [B,H,N,HD]*scale ; MODE 1: bf16 transposed [B,H,HD,N]*scale ;
// MODE 2: f32 [M,NN] + bias.  XCD-chunked block swizzle (nwg=512, 512%8==0).
template <int MODE>
__global__ __launch_bounds__(256) void gemm_bt(const u16* __restrict__ A,
                                               const u16* __restrict__ Bt,
                                               void* __restrict__ Cout,
                                               const float* __restrict__ bias,
                                               float scale, int M, int NN, int K) {
    __shared__ __align__(16) u16 lga[128 * 64];
    __shared__ __align__(16) u16 lgb[128 * 64];
    const int tid  = threadIdx.x;
    const int lane = tid & 63, wave = tid >> 6;
    const int wm = wave >> 1, wn = wave & 1;
    // T1: XCD i executes a contiguous run of 64 work items (8 A-panels + whole B in its L2)
    int lin = blockIdx.x + gridDim.x * blockIdx.y;
    int w   = (lin & 7) * 64 + (lin >> 3);
    const int row0 = (w >> 3) * 128, col0 = (w & 7) * 128;

    f32x4 acc[4][4] = {};

    auto stageLds = [&](const u16* G, u16* L, int rowbase, int k0) {
        #pragma unroll
        for (int i = 0; i < 4; i++) {
            int rb = wave * 32 + i * 8;
            int r  = rb + (lane >> 3);
            int cc = (lane & 7) ^ (lane >> 3);
            gl_lds16(G + (size_t)(rowbase + r) * K + k0 + cc * 8, L + rb * 64);
        }
    };

    for (int k0 = 0; k0 < K; k0 += 64) {
        stageLds(A,  lga, row0, k0);
        stageLds(Bt, lgb, col0, k0);
        __syncthreads();
        #pragma unroll
        for (int kk = 0; kk < 2; kk++) {
            s16x8 af[4], bfr[4];
            #pragma unroll
            for (int mi = 0; mi < 4; mi++) {
                int r = wm * 64 + mi * 16 + (lane & 15);
                int sc = (kk * 4 + (lane >> 4)) ^ (lane & 7);
                af[mi] = *(const s16x8*)(&lga[r * 64 + sc * 8]);
            }
            #pragma unroll
            for (int ni = 0; ni < 4; ni++) {
                int r = wn * 64 + ni * 16 + (lane & 15);
                int sc = (kk * 4 + (lane >> 4)) ^ (lane & 7);
                bfr[ni] = *(const s16x8*)(&lgb[r * 64 + sc * 8]);
            }
            #pragma unroll
            for (int mi = 0; mi < 4; mi++)
                #pragma unroll
                for (int ni = 0; ni < 4; ni++)
                    acc[mi][ni] = __builtin_amdgcn_mfma_f32_16x16x32_bf16(
                        af[mi], bfr[ni], acc[mi][ni], 0, 0, 0);
        }
        __syncthreads();
    }

    #pragma unroll
    for (int mi = 0; mi < 4; mi++) {
        #pragma unroll
        for (int ni = 0; ni < 4; ni++) {
            #pragma unroll
            for (int r = 0; r < 4; r++) {
                int grow = row0 + wm * 64 + mi * 16 + ((lane >> 4) << 2) + r;
                int gcol = col0 + wn * 64 + ni * 16 + (lane & 15);
                float vv = acc[mi][ni][r];
                if (MODE == 2) {
                    ((float*)Cout)[(size_t)grow * NN + gcol] = vv + bias[gcol];
                } else {
                    vv *= scale;
                    int bb = grow >> 11, n = grow & (N_ - 1);
                    int hh = gcol >> 7,  d = gcol & (HD_ - 1);
                    size_t idx = (MODE == 0)
                        ? ((size_t)(bb * H_ + hh) * N_ + n) * HD_ + d
                        : ((size_t)(bb * H_ + hh) * HD_ + d) * N_ + n;
                    ((u16*)Cout)[idx] = f2bf(vv);
                }
            }
        }
    }
}

// ---------------------------------------------------------------- gated flash attention (swapped)
// 32x32 MFMA, S^T = K·Q^T (lane owns q-row = lane&31; R4/R6-verified math).
// T15 pipeline: PV(t-1) issued between QK(t) and softmax(t) VALU (register-independent,
// scheduler interleaves); vt triple-buffered so tile t-1 survives stage of t+1.
// transT: [B,N(kv),N(q)] f32 -> gate reads 128B-coalesced.  One barrier per tile.
__global__ __launch_bounds__(256, 2) void attn_swapped(const u16* __restrict__ Qh,
                                                       const u16* __restrict__ Kh,
                                                       const u16* __restrict__ Vt,
                                                       const float* __restrict__ transT,
                                                       u16* __restrict__ xout) {
    __shared__ __align__(16) u16 kt[2][64 * 128];   // K [kv=64][d=128], slot = c ^ mK(r)
    __shared__ __align__(16) u16 vt[3][128 * 64];   // Vt [d=128][kv=64], slot = c ^ mV(r)

    const int tid = threadIdx.x, lane = tid & 63, wave = tid >> 6;
    const int lq = lane & 31, hl = lane >> 5;

    // XCD chunking: each XCD gets 64 consecutive work items (one b, 4 heads)
    int lin = blockIdx.x + 16 * (blockIdx.y + 8 * blockIdx.z);
    int nl  = (lin & 7) * 64 + (lin >> 3);
    const int qt = nl & 15, hh = (nl >> 4) & 7, b = nl >> 7;
    const int q0 = qt * 128 + wave * 32;
    const int q  = q0 + lq;                         // this lane's q row

    const u16* Qbh = Qh + (size_t)(b * H_ + hh) * N_ * HD_;
    const u16* Kbh = Kh + (size_t)(b * H_ + hh) * N_ * HD_;
    const u16* Vbh = Vt + (size_t)(b * H_ + hh) * HD_ * N_;
    const float* tTq = transT + (size_t)b * N_ * N_ + q;   // + kv*N per element

    // Q fragments (B-operand): qf[s] = Q[q][s*16 + hl*8 + j]
    s16x8 qf[8];
    #pragma unroll
    for (int s = 0; s < 8; s++)
        qf[s] = *(const s16x8*)(Qbh + (size_t)q * HD_ + s * 16 + hl * 8);

    // staging: linear LDS dest; inverse swizzle applied on the GLOBAL chunk index
    auto stageKV = [&](int kv0, int kbi, int vbi) {
        #pragma unroll
        for (int i = 0; i < 4; i++) {
            int rk = wave * 16 + i * 4 + (lane >> 4);
            int ck = (lane & 15) ^ (rk & 15) ^ ((rk & 16) >> 2);
            gl_lds16(Kbh + (size_t)(kv0 + rk) * HD_ + ck * 8,
                     &kt[kbi][(wave * 16 + i * 4) * 128]);
            int rv = wave * 32 + i * 8 + (lane >> 3);
            int cv = (lane & 7) ^ (rv & 7) ^ ((rv >> 3) & 3);
            gl_lds16(Vbh + (size_t)rv * N_ + kv0 + cv * 8,
                     &vt[vbi][(wave * 32 + i * 8) * 64]);
        }
    };

    const int mKl = (lq & 15) ^ ((lq & 16) >> 2);   // read-side masks (r-bits from lq only)
    const int mVl = (lq & 7) ^ ((lq >> 3) & 3);

    float m = -3.0e38f, l = 0.f;
    f32x16 aoT[4] = {};    // O^T[d=(reg&3)+8*(reg>>2)+4*hl+32*dt][q=lq]
    s16x8 pfA[4], pfB[4];  // P fragments, double-pipelined (static names, rule #20)
    int kc = 0, vc = 0, vprev = 2;   // LDS buffer of tile it (kt/vt) and tile it-1 (vt)

    stageKV(0, 0, 0);
    __syncthreads();

    auto body = [&](int it, s16x8 (&pprev)[4], s16x8 (&pcur)[4], bool doPV) {
        const int kv0 = it * 64;
        const int vnext = (vc == 2) ? 0 : vc + 1;
        if (it + 1 < N_ / 64) stageKV(kv0 + 64, kc ^ 1, vnext);

        // gate values, coalesced from transT: kv = (idx&3) + 8*(idx>>2) + 4*hl + 32*ni
        float tt[2][16];
        #pragma unroll
        for (int ni = 0; ni < 2; ni++)
            #pragma unroll
            for (int idx = 0; idx < 16; idx++) {
                int kv = (idx & 3) + 8 * (idx >> 2) + 4 * hl + 32 * ni;
                tt[ni][idx] = tTq[(size_t)(kv0 + kv) * N_];
            }

        // S^T = K · Q^T
        f32x16 sT[2] = {};
        __builtin_amdgcn_s_setprio(1);
        #pragma unroll
        for (int s = 0; s < 8; s++)
            #pragma unroll
            for (int ni = 0; ni < 2; ni++) {
                int r = ni * 32 + lq;
                int slot = (2 * s + hl) ^ mKl;
                s16x8 kf = *(const s16x8*)(&kt[kc][r * 128 + slot * 8]);
                sT[ni] = __builtin_amdgcn_mfma_f32_32x32x16_bf16(kf, qf[s], sT[ni], 0, 0, 0);
            }
        __builtin_amdgcn_s_setprio(0);

        // gate + lane-local row max (independent of PV below -> scheduler interleaves)
        float mx = -3.0e38f;
        #pragma unroll
        for (int ni = 0; ni < 2; ni++)
            #pragma unroll
            for (int idx = 0; idx < 16; idx++) {
                float g = sT[ni][idx] * tt[ni][idx];
                sT[ni][idx] = g;
                mx = fmaxf(mx, g);
            }
        mx = fmaxf(mx, __shfl_xor(mx, 32));

        // T15: O^T += V^T · P^T(it-1) — register-independent of gate/mx above;
        // aoT dependency orders it before the rescale below.
        if (doPV) {
            #pragma unroll
            for (int dt = 0; dt < 4; dt++)
                #pragma unroll
                for (int sp = 0; sp < 4; sp++) {
                    int r = dt * 32 + lq;
                    int slot = (2 * sp + hl) ^ mVl;
                    s16x8 vf = *(const s16x8*)(&vt[vprev][r * 64 + slot * 8]);
                    aoT[dt] = __builtin_amdgcn_mfma_f32_32x32x16_bf16(vf, pprev[sp], aoT[dt], 0, 0, 0);
                }
        }

        // defer-rescale (T13)
        if (__any(mx > m + 8.0f)) {
            float mn = fmaxf(m, mx);
            float sfv = __builtin_amdgcn_exp2f(m - mn);
            m = mn;
            l *= sfv;
            #pragma unroll
            for (int dt = 0; dt < 4; dt++)
                #pragma unroll
                for (int e = 0; e < 16; e++) aoT[dt][e] *= sfv;
        }

        // P = exp2(g - m); denom includes ALL entries; PV term zeroed where g==0
        float rs = 0.f;
        #pragma unroll
        for (int ni = 0; ni < 2; ni++)
            #pragma unroll
            for (int e = 0; e < 16; e++) {
                float g = sT[ni][e];
                float p = __builtin_amdgcn_exp2f(g - m);
                rs += p;
                sT[ni][e] = (g != 0.0f) ? p : 0.0f;
            }
        rs += __shfl_xor(rs, 32);
        l += rs;

        // pack P -> A-frags: 16 cvt_pk + 8 permlane32_swap (R4-verified)
        #pragma unroll
        for (int sp = 0; sp < 4; sp++) {
            const int ni = sp >> 1;
            const int ru = (2 * sp) & 3, rv2 = (2 * sp + 1) & 3;
            unsigned u0 = pk_bf16(sT[ni][ru * 4 + 0], sT[ni][ru * 4 + 1]);
            unsigned u1 = pk_bf16(sT[ni][ru * 4 + 2], sT[ni][ru * 4 + 3]);
            unsigned v0 = pk_bf16(sT[ni][rv2 * 4 + 0], sT[ni][rv2 * 4 + 1]);
            unsigned v1 = pk_bf16(sT[ni][rv2 * 4 + 2], sT[ni][rv2 * 4 + 3]);
            pl32_swap(u0, v0);
            pl32_swap(u1, v1);
            u32x4 w = {u0, u1, v0, v1};
            pcur[sp] = __builtin_bit_cast(s16x8, w);
        }

        vprev = vc; vc = vnext; kc ^= 1;
        __syncthreads();   // kt[old]/vt reads done; next-tile gl_lds drained
    };

    body(0, pfA, pfA, false);                  // P(0) -> pfA
    #pragma unroll 1
    for (int j = 0; j < 15; j++) {
        body(2 * j + 1, pfA, pfB, true);       // PV(2j),   P(2j+1) -> pfB
        body(2 * j + 2, pfB, pfA, true);       // PV(2j+1), P(2j+2) -> pfA
    }
    body(31, pfA, pfB, true);                  // PV(30), P(31) -> pfB

    // tail: O^T += V^T · P^T(31)
    #pragma unroll
    for (int dt = 0; dt < 4; dt++)
        #pragma unroll
        for (int sp = 0; sp < 4; sp++) {
            int r = dt * 32 + lq;
            int slot = (2 * sp + hl) ^ mVl;
            s16x8 vf = *(const s16x8*)(&vt[vprev][r * 64 + slot * 8]);
            aoT[dt] = __builtin_amdgcn_mfma_f32_32x32x16_bf16(vf, pfB[sp], aoT[dt], 0, 0, 0);
        }

    // normalize and write x[b, n=q, hh*HD + d]; d = (reg&3) + 8*(reg>>2) + 4*hl + 32*dt
    float inv = 1.0f / l;
    u16* orow = xout + ((size_t)(b * N_ + q)) * DIM_ + hh * HD_;
    #pragma unroll
    for (int dt = 0; dt < 4; dt++)
        #pragma unroll
        for (int r2 = 0; r2 < 4; r2++) {
            u16x4 ov;
            #pragma unroll
            for (int e = 0; e < 4; e++)
                ov[e] = f2bf(aoT[dt][r2 * 4 + e] * inv);
            *(u16x4*)(orow + dt * 32 + r2 * 8 + hl * 4) = ov;
        }
}

// ---------------------------------------------------------------- R3 fallback attention
// (used only if ws_size can't hold transT; proven at 155.7 us)
__global__ __launch_bounds__(512) void attn_fb(const u16* __restrict__ Qh,
                                               const u16* __restrict__ Kh,
                                               const u16* __restrict__ Vt,
                                               const float* __restrict__ trans,
                                               u16* __restrict__ xout) {
    __shared__ __align__(16) u16 kt[64 * 128];
    __shared__ __align__(16) u16 vt[128 * 64];
    __shared__ __align__(16) u16 plds[8][16 * 72];

    const int tid = threadIdx.x, lane = tid & 63, wave = tid >> 6;
    const int qt = blockIdx.x, h = blockIdx.y, b = blockIdx.z;
    const int qrow_base = qt * 128 + wave * 16;

    const u16* Qbh = Qh + (size_t)(b * H_ + h) * N_ * HD_;
    const u16* Kbh = Kh + (size_t)(b * H_ + h) * N_ * HD_;
    const u16* Vbh = Vt + (size_t)(b * H_ + h) * HD_ * N_;
    const float* trow = trans + (size_t)b * N_ * N_
                      + (size_t)(qrow_base + ((lane >> 4) << 2)) * N_ + (lane & 15);

    s16x8 qf[4];
    {
        int r = qrow_base + (lane & 15);
        #pragma unroll
        for (int kd = 0; kd < 4; kd++)
            qf[kd] = *(const s16x8*)(Qbh + (size_t)r * HD_ + kd * 32 + ((lane >> 4) << 3));
    }
    auto stageKV = [&](int kv0) {
        int rbk = wave * 8, rbv = wave * 16;
        #pragma unroll
        for (int j = 0; j < 2; j++) {
            int c = j * 64 + lane;
            int rk = rbk + (c >> 4), ck = (c & 15) ^ (rk & 15);
            gl_lds16(Kbh + (size_t)(kv0 + rk) * HD_ + ck * 8, kt + rbk * 128 + j * 512);
            int rv = rbv + (c >> 3), cv = (c & 7) ^ (rv & 7);
            gl_lds16(Vbh + (size_t)rv * N_ + kv0 + cv * 8, vt + rbv * 64 + j * 512);
        }
    };

    float m[4], l[4];
    #pragma unroll
    for (int r = 0; r < 4; r++) { m[r] = -3.0e38f; l[r] = 0.f; }
    f32x4 ao[8] = {};

    for (int kv0 = 0; kv0 < N_; kv0 += 64) {
        stageKV(kv0);
        __syncthreads();
        f32x4 s[4] = {};
        #pragma unroll
        for (int kd = 0; kd < 4; kd++)
            #pragma unroll
            for (int ni = 0; ni < 4; ni++) {
                int r = ni * 16 + (lane & 15);
                int sc = (kd * 4 + (lane >> 4)) ^ (lane & 15);
                s16x8 bfr = *(const s16x8*)(&kt[r * 128 + sc * 8]);
                s[ni] = __builtin_amdgcn_mfma_f32_16x16x32_bf16(qf[kd], bfr, s[ni], 0, 0, 0);
            }
        float pmax[4] = {-3.0e38f, -3.0e38f, -3.0e38f, -3.0e38f};
        #pragma unroll
        for (int ni = 0; ni < 4; ni++)
            #pragma unroll
            for (int r = 0; r < 4; r++) {
                float tt = trow[(size_t)r * N_ + kv0 + ni * 16];
                float gg = s[ni][r] * tt;
                s[ni][r] = gg;
                pmax[r] = fmaxf(pmax[r], gg);
            }
        #pragma unroll
        for (int r = 0; r < 4; r++) {
            float p = pmax[r];
            p = fmaxf(p, __shfl_xor(p, 1));
            p = fmaxf(p, __shfl_xor(p, 2));
            p = fmaxf(p, __shfl_xor(p, 4));
            p = fmaxf(p, __shfl_xor(p, 8));
            pmax[r] = p;
        }
        bool need = false;
        #pragma unroll
        for (int r = 0; r < 4; r++) need = need || (pmax[r] > m[r] + 8.0f);
        if (__any(need)) {
            #pragma unroll
            for (int r = 0; r < 4; r++) {
                float mn = fmaxf(m[r], pmax[r]);
                float sfv = __builtin_amdgcn_exp2f(m[r] - mn);
                m[r] = mn; l[r] *= sfv;
                #pragma unroll
                for (int t = 0; t < 8; t++) ao[t][r] *= sfv;
            }
        }
        float rowsum[4] = {0.f, 0.f, 0.f, 0.f};
        u16* pw = &plds[wave][0];
        #pragma unroll
        for (int ni = 0; ni < 4; ni++)
            #pragma unroll
            for (int r = 0; r < 4; r++) {
                float gg = s[ni][r];
                float e = __builtin_amdgcn_exp2f(gg - m[r]);
                rowsum[r] += e;
                float pe = (gg != 0.0f) ? e : 0.0f;
                pw[(((lane >> 4) << 2) + r) * 72 + ni * 16 + (lane & 15)] = f2bf(pe);
            }
        #pragma unroll
        for (int r = 0; r < 4; r++) {
            float ssum = rowsum[r];
            ssum += __shfl_xor(ssum, 1);
            ssum += __shfl_xor(ssum, 2);
            ssum += __shfl_xor(ssum, 4);
            ssum += __shfl_xor(ssum, 8);
            l[r] += ssum;
        }
        #pragma unroll
        for (int kk = 0; kk < 2; kk++) {
            s16x8 pa = *(const s16x8*)(&pw[(lane & 15) * 72 + kk * 32 + ((lane >> 4) << 3)]);
            #pragma unroll
            for (int t = 0; t < 8; t++) {
                int r = t * 16 + (lane & 15);
                int sc = (kk * 4 + (lane >> 4)) ^ (r & 7);
                s16x8 vb = *(const s16x8*)(&vt[r * 64 + sc * 8]);
                ao[t] = __builtin_amdgcn_mfma_f32_16x16x32_bf16(pa, vb, ao[t], 0, 0, 0);
            }
        }
        __syncthreads();
    }
    #pragma unroll
    for (int r = 0; r < 4; r++) {
        float inv = 1.0f / l[r];
        int n = qrow_base + ((lane >> 4) << 2) + r;
        u16* orow = xout + ((size_t)(b * N_ + n)) * DIM_ + h * HD_;
        #pragma unroll
        for (int t = 0; t < 8; t++)
            orow[t * 16 + (lane & 15)] = f2bf(ao[t][r] * inv);
    }
}

// ---------------------------------------------------------------- launch
extern "C" void kernel_launch(void* const* d_in, const int* in_sizes, int n_in,
                              void* d_out, int out_size, void* d_ws, size_t ws_size,
                              hipStream_t stream) {
    const float* q     = (const float*)d_in[0];
    const float* k     = (const float*)d_in[1];
    const float* v     = (const float*)d_in[2];
    const float* trans = (const float*)d_in[3];
    const float* Wq    = (const float*)d_in[4];
    const float* Wk    = (const float*)d_in[5];
    const float* Wv    = (const float*)d_in[6];
    const float* Wp    = (const float*)d_in[7];
    const float* bp    = (const float*)d_in[8];

    // workspace map:
    //  [0,16M): tmp bf16 q/k/v staging, later attention out x
    //  [16M..24M): Wq,Wk,Wv,Wp bf16 ; [24..40M): Qh ; [40..56M): Kh ; [56..72M): Vt
    //  [72M..136M): transT (only if ws_size permits)
    char* ws = (char*)d_ws;
    u16* tmp = (u16*)(ws);
    u16* wqb = (u16*)(ws + (16u << 20));
    u16* wkb = (u16*)(ws + (18u << 20));
    u16* wvb = (u16*)(ws + (20u << 20));
    u16* wpb = (u16*)(ws + (22u << 20));
    u16* QhB = (u16*)(ws + (24u << 20));
    u16* KhB = (u16*)(ws + (40u << 20));
    u16* VtB = (u16*)(ws + (56u << 20));
    float* tT = (float*)(ws + (72u << 20));
    u16* xb  = tmp;
    const bool big = ws_size >= (136ull << 20);

    dim3 blk(256);
    cvt_w4<<<dim3(512, 4), blk, 0, stream>>>(Wq, Wk, Wv, Wp, wqb);

    dim3 pg(DIM_ / 128, MTOK / 128);   // (8, 64)

    cvt_f32_bf16<<<dim3(8192), blk, 0, stream>>>(q, tmp, MTOK * DIM_);
    gemm_bt<0><<<pg, blk, 0, stream>>>(tmp, wqb, QhB, nullptr, QSCALE_, MTOK, DIM_, DIM_);
    cvt_f32_bf16<<<dim3(8192), blk, 0, stream>>>(k, tmp, MTOK * DIM_);
    gemm_bt<0><<<pg, blk, 0, stream>>>(tmp, wkb, KhB, nullptr, 1.0f, MTOK, DIM_, DIM_);
    cvt_f32_bf16<<<dim3(8192), blk, 0, stream>>>(v, tmp, MTOK * DIM_);
    gemm_bt<1><<<pg, blk, 0, stream>>>(tmp, wvb, VtB, nullptr, 1.0f, MTOK, DIM_, DIM_);

    if (big) {
        transpose_f32<<<dim3(N_ / 64, N_ / 64, B_), blk, 0, stream>>>(trans, tT);
        attn_swapped<<<dim3(16, 8, 4), dim3(256), 0, stream>>>(QhB, KhB, VtB, tT, xb);
    } else {
        attn_fb<<<dim3(N_ / 128, H_, B_), dim3(512), 0, stream>>>(QhB, KhB, VtB, trans, xb);
    }

    gemm_bt<2><<<pg, blk, 0, stream>>>(xb, wpb, d_out, bp, 1.0f, MTOK, DIM_, DIM_);
}

// Round 8
// 266.399 us; speedup vs baseline: 1.1047x; 1.1047x over previous
//
#include <hip/hip_runtime.h>
#include <hip/hip_bf16.h>
#include <stdint.h>

// Problem constants (fixed by the reference)
#define B_    4
#define N_    2048
#define DIM_  1024
#define H_    8
#define HD_   128
#define MTOK  (B_ * N_)          // 8192 tokens
#define SCALE_  0.08838834764831845f   // HD^-0.5
#define LOG2E_  1.4426950408889634f
#define QSCALE_ (SCALE_ * LOG2E_)      // folded into Q projection epilogue

typedef unsigned short u16;
typedef __attribute__((ext_vector_type(4)))  float f32x4;
typedef __attribute__((ext_vector_type(16))) float f32x16;
typedef __attribute__((ext_vector_type(8)))  short s16x8;   // 8 bf16 — MFMA A/B frag
typedef __attribute__((ext_vector_type(8)))  u16  u16x8;
typedef __attribute__((ext_vector_type(4)))  u16  u16x4;
typedef __attribute__((ext_vector_type(4)))  unsigned u32x4;

__device__ __forceinline__ u16 f2bf(float f) {
    uint32_t i = __builtin_bit_cast(uint32_t, f);
    return (u16)((i + 0x7FFFu + ((i >> 16) & 1u)) >> 16);   // RNE
}
// v_cvt_pk_bf16_f32: packs (a,b) -> u32 [b_bf16 | a_bf16] (a in low 16), RNE
__device__ __forceinline__ unsigned pk_bf16(float a, float b) {
    unsigned r;
    asm("v_cvt_pk_bf16_f32 %0, %1, %2" : "=v"(r) : "v"(a), "v"(b));
    return r;
}
// v_permlane32_swap_b32: a' = {a.lo32lanes, b.lo32lanes}, b' = {a.hi, b.hi}
__device__ __forceinline__ void pl32_swap(unsigned &a, unsigned &b) {
    asm volatile("v_permlane32_swap_b32 %0, %1" : "+v"(a), "+v"(b));
}
// direct global->LDS, 16B per lane; LDS dest = wave-uniform base + lane*16
__device__ __forceinline__ void gl_lds16(const u16* g, u16* l) {
    __builtin_amdgcn_global_load_lds((const __attribute__((address_space(1))) void*)g,
                                     (__attribute__((address_space(3))) void*)l,
                                     16, 0, 0);
}

// ---------------------------------------------------------------- cvt f32->bf16 (fallback path)
__global__ __launch_bounds__(256) void cvt_f32_bf16(const float* __restrict__ src,
                                                    u16* __restrict__ dst, int n) {
    int i = (blockIdx.x * 256 + threadIdx.x) * 4;
    int stride = gridDim.x * 256 * 4;
    for (; i < n; i += stride) {
        float4 v = *(const float4*)(src + i);
        u16x4 o;
        o.x = f2bf(v.x); o.y = f2bf(v.y); o.z = f2bf(v.z); o.w = f2bf(v.w);
        *(u16x4*)(dst + i) = o;
    }
}

// ---------------------------------------------------------------- q/k/v cvt, one launch
__global__ __launch_bounds__(256) void cvt3(const float* __restrict__ q,
                                            const float* __restrict__ k,
                                            const float* __restrict__ v,
                                            u16* __restrict__ qb,
                                            u16* __restrict__ kb,
                                            u16* __restrict__ vb) {
    const float* s = blockIdx.y == 0 ? q : blockIdx.y == 1 ? k : v;
    u16* d = blockIdx.y == 0 ? qb : blockIdx.y == 1 ? kb : vb;
    int i = (blockIdx.x * 256 + threadIdx.x) * 8;      // grid.x=4096 covers 8M elems
    float4 a = *(const float4*)(s + i);
    float4 b = *(const float4*)(s + i + 4);
    u32x4 w = {pk_bf16(a.x, a.y), pk_bf16(a.z, a.w), pk_bf16(b.x, b.y), pk_bf16(b.z, b.w)};
    *(u16x8*)(d + i) = __builtin_bit_cast(u16x8, w);
}

// ---------------------------------------------------------------- weight cvt (4 tensors, one launch)
__global__ __launch_bounds__(256) void cvt_w4(const float* __restrict__ s0,
                                              const float* __restrict__ s1,
                                              const float* __restrict__ s2,
                                              const float* __restrict__ s3,
                                              u16* __restrict__ dst) {
    const float* s = blockIdx.y == 0 ? s0 : blockIdx.y == 1 ? s1 : blockIdx.y == 2 ? s2 : s3;
    u16* d = dst + (size_t)blockIdx.y * (DIM_ * DIM_);
    int i = (blockIdx.x * 256 + threadIdx.x) * 8;          // grid.x=512 covers 1M elems
    float4 a = *(const float4*)(s + i);
    float4 b = *(const float4*)(s + i + 4);
    u32x4 w = {pk_bf16(a.x, a.y), pk_bf16(a.z, a.w), pk_bf16(b.x, b.y), pk_bf16(b.z, b.w)};
    *(u16x8*)(d + i) = __builtin_bit_cast(u16x8, w);
}

// ---------------------------------------------------------------- trans transpose (f32, per-batch)
// out[b][c][r] = in[b][r][c]; float4 on both global sides, scalar LDS ([64][65] = 2-way free)
__global__ __launch_bounds__(256) void transpose_f32(const float* __restrict__ in,
                                                     float* __restrict__ out) {
    __shared__ float t[64][65];
    const int r0 = blockIdx.y * 64, c0 = blockIdx.x * 64;
    const float* ib = in + (size_t)blockIdx.z * N_ * N_;
    float* ob = out + (size_t)blockIdx.z * N_ * N_;
    const int lr = threadIdx.x >> 4;      // 0..15
    const int lc = threadIdx.x & 15;      // 0..15 (x4 cols)
    #pragma unroll
    for (int i = 0; i < 4; i++) {
        int row = i * 16 + lr;
        float4 v = *(const float4*)(ib + (size_t)(r0 + row) * N_ + c0 + lc * 4);
        t[row][lc * 4 + 0] = v.x; t[row][lc * 4 + 1] = v.y;
        t[row][lc * 4 + 2] = v.z; t[row][lc * 4 + 3] = v.w;
    }
    __syncthreads();
    #pragma unroll
    for (int i = 0; i < 4; i++) {
        int row = i * 16 + lr;
        float4 w;
        w.x = t[lc * 4 + 0][row]; w.y = t[lc * 4 + 1][row];
        w.z = t[lc * 4 + 2][row]; w.w = t[lc * 4 + 3][row];
        *(float4*)(ob + (size_t)(c0 + row) * N_ + r0 + lc * 4) = w;
    }
}

// ---------------------------------------------------------------- GEMM C = A @ Bt^T  (R3 + T1, R7-proven)
// A [M,K] bf16 row-major; Bt [NN,K] bf16 row-major; both gl_lds staged (pre-swizzled source).
// MODE 0: bf16 head-split [B,H,N,HD]*scale ; MODE 1: bf16 transposed [B,H,HD,N]*scale ;
// MODE 2: f32 [M,NN] + bias.  XCD-chunked block swizzle (nwg=512, 512%8==0).
template <int MODE>
__global__ __launch_bounds__(256) void gemm_bt(const u16* __restrict__ A,
                                               const u16* __restrict__ Bt,
                                               void* __restrict__ Cout,
                                               const float* __restrict__ bias,
                                               float scale, int M, int NN, int K) {
    __shared__ __align__(16) u16 lga[128 * 64];
    __shared__ __align__(16) u16 lgb[128 * 64];
    const int tid  = threadIdx.x;
    const int lane = tid & 63, wave = tid >> 6;
    const int wm = wave >> 1, wn = wave & 1;
    // T1: XCD i executes a contiguous run of 64 work items (8 A-panels + whole B in its L2)
    int lin = blockIdx.x + gridDim.x * blockIdx.y;
    int w   = (lin & 7) * 64 + (lin >> 3);
    const int row0 = (w >> 3) * 128, col0 = (w & 7) * 128;

    f32x4 acc[4][4] = {};

    auto stageLds = [&](const u16* G, u16* L, int rowbase, int k0) {
        #pragma unroll
        for (int i = 0; i < 4; i++) {
            int rb = wave * 32 + i * 8;
            int r  = rb + (lane >> 3);
            int cc = (lane & 7) ^ (lane >> 3);
            gl_lds16(G + (size_t)(rowbase + r) * K + k0 + cc * 8, L + rb * 64);
        }
    };

    for (int k0 = 0; k0 < K; k0 += 64) {
        stageLds(A,  lga, row0, k0);
        stageLds(Bt, lgb, col0, k0);
        __syncthreads();
        #pragma unroll
        for (int kk = 0; kk < 2; kk++) {
            s16x8 af[4], bfr[4];
            #pragma unroll
            for (int mi = 0; mi < 4; mi++) {
                int r = wm * 64 + mi * 16 + (lane & 15);
                int sc = (kk * 4 + (lane >> 4)) ^ (lane & 7);
                af[mi] = *(const s16x8*)(&lga[r * 64 + sc * 8]);
            }
            #pragma unroll
            for (int ni = 0; ni < 4; ni++) {
                int r = wn * 64 + ni * 16 + (lane & 15);
                int sc = (kk * 4 + (lane >> 4)) ^ (lane & 7);
                bfr[ni] = *(const s16x8*)(&lgb[r * 64 + sc * 8]);
            }
            #pragma unroll
            for (int mi = 0; mi < 4; mi++)
                #pragma unroll
                for (int ni = 0; ni < 4; ni++)
                    acc[mi][ni] = __builtin_amdgcn_mfma_f32_16x16x32_bf16(
                        af[mi], bfr[ni], acc[mi][ni], 0, 0, 0);
        }
        __syncthreads();
    }

    #pragma unroll
    for (int mi = 0; mi < 4; mi++) {
        #pragma unroll
        for (int ni = 0; ni < 4; ni++) {
            #pragma unroll
            for (int r = 0; r < 4; r++) {
                int grow = row0 + wm * 64 + mi * 16 + ((lane >> 4) << 2) + r;
                int gcol = col0 + wn * 64 + ni * 16 + (lane & 15);
                float vv = acc[mi][ni][r];
                if (MODE == 2) {
                    ((float*)Cout)[(size_t)grow * NN + gcol] = vv + bias[gcol];
                } else {
                    vv *= scale;
                    int bb = grow >> 11, n = grow & (N_ - 1);
                    int hh = gcol >> 7,  d = gcol & (HD_ - 1);
                    size_t idx = (MODE == 0)
                        ? ((size_t)(bb * H_ + hh) * N_ + n) * HD_ + d
                        : ((size_t)(bb * H_ + hh) * HD_ + d) * N_ + n;
                    ((u16*)Cout)[idx] = f2bf(vv);
                }
            }
        }
    }
}

// ---------------------------------------------------------------- gated flash attention (swapped)
// R6-proven (114.5 us): 32x32 MFMA, S^T = K·Q^T (lane owns q-row = lane&31).
// transT: [B,N(kv),N(q)] f32 -> gate reads 128B-coalesced.  4 waves/block, 512 blocks,
// double-buffered K/V (1 barrier/tile), bank-spread XOR swizzles, XCD-chunked grid.
__global__ __launch_bounds__(256, 2) void attn_swapped(const u16* __restrict__ Qh,
                                                       const u16* __restrict__ Kh,
                                                       const u16* __restrict__ Vt,
                                                       const float* __restrict__ transT,
                                                       u16* __restrict__ xout) {
    __shared__ __align__(16) u16 kt[2][64 * 128];   // K [kv=64][d=128], slot = c ^ mK(r)
    __shared__ __align__(16) u16 vt[2][128 * 64];   // Vt [d=128][kv=64], slot = c ^ mV(r)

    const int tid = threadIdx.x, lane = tid & 63, wave = tid >> 6;
    const int lq = lane & 31, hl = lane >> 5;

    // XCD chunking: each XCD gets 64 consecutive work items (one b, 4 heads)
    int lin = blockIdx.x + 16 * (blockIdx.y + 8 * blockIdx.z);
    int nl  = (lin & 7) * 64 + (lin >> 3);
    const int qt = nl & 15, hh = (nl >> 4) & 7, b = nl >> 7;
    const int q0 = qt * 128 + wave * 32;
    const int q  = q0 + lq;                         // this lane's q row

    const u16* Qbh = Qh + (size_t)(b * H_ + hh) * N_ * HD_;
    const u16* Kbh = Kh + (size_t)(b * H_ + hh) * N_ * HD_;
    const u16* Vbh = Vt + (size_t)(b * H_ + hh) * HD_ * N_;
    const float* tTq = transT + (size_t)b * N_ * N_ + q;   // + kv*N per element

    // Q fragments (B-operand): qf[s] = Q[q][s*16 + hl*8 + j]
    s16x8 qf[8];
    #pragma unroll
    for (int s = 0; s < 8; s++)
        qf[s] = *(const s16x8*)(Qbh + (size_t)q * HD_ + s * 16 + hl * 8);

    // staging: linear LDS dest; inverse swizzle applied on the GLOBAL chunk index
    auto stageKV = [&](int kv0, int bi) {
        #pragma unroll
        for (int i = 0; i < 4; i++) {
            int rk = wave * 16 + i * 4 + (lane >> 4);
            int ck = (lane & 15) ^ (rk & 15) ^ ((rk & 16) >> 2);
            gl_lds16(Kbh + (size_t)(kv0 + rk) * HD_ + ck * 8,
                     &kt[bi][(wave * 16 + i * 4) * 128]);
            int rv = wave * 32 + i * 8 + (lane >> 3);
            int cv = (lane & 7) ^ (rv & 7) ^ ((rv >> 3) & 3);
            gl_lds16(Vbh + (size_t)rv * N_ + kv0 + cv * 8,
                     &vt[bi][(wave * 32 + i * 8) * 64]);
        }
    };

    const int mKl = (lq & 15) ^ ((lq & 16) >> 2);   // read-side masks (r-bits from lq only)
    const int mVl = (lq & 7) ^ ((lq >> 3) & 3);

    float m = -3.0e38f, l = 0.f;
    f32x16 aoT[4] = {};    // O^T[d=(reg&3)+8*(reg>>2)+4*hl+32*dt][q=lq]

    stageKV(0, 0);
    __syncthreads();

    for (int it = 0; it < N_ / 64; it++) {
        const int kv0 = it * 64, cur = it & 1;
        if (it + 1 < N_ / 64) stageKV(kv0 + 64, cur ^ 1);   // drained by end-of-iter barrier

        // gate values, coalesced from transT: kv = (idx&3) + 8*(idx>>2) + 4*hl + 32*ni
        float tt[2][16];
        #pragma unroll
        for (int ni = 0; ni < 2; ni++)
            #pragma unroll
            for (int idx = 0; idx < 16; idx++) {
                int kv = (idx & 3) + 8 * (idx >> 2) + 4 * hl + 32 * ni;
                tt[ni][idx] = tTq[(size_t)(kv0 + kv) * N_];
            }

        // S^T = K · Q^T
        f32x16 sT[2] = {};
        __builtin_amdgcn_s_setprio(1);
        #pragma unroll
        for (int s = 0; s < 8; s++)
            #pragma unroll
            for (int ni = 0; ni < 2; ni++) {
                int r = ni * 32 + lq;
                int slot = (2 * s + hl) ^ mKl;
                s16x8 kf = *(const s16x8*)(&kt[cur][r * 128 + slot * 8]);
                sT[ni] = __builtin_amdgcn_mfma_f32_32x32x16_bf16(kf, qf[s], sT[ni], 0, 0, 0);
            }
        __builtin_amdgcn_s_setprio(0);

        // gate + lane-local row max (one cross-half exchange)
        float mx = -3.0e38f;
        #pragma unroll
        for (int ni = 0; ni < 2; ni++)
            #pragma unroll
            for (int idx = 0; idx < 16; idx++) {
                float g = sT[ni][idx] * tt[ni][idx];
                sT[ni][idx] = g;
                mx = fmaxf(mx, g);
            }
        mx = fmaxf(mx, __shfl_xor(mx, 32));

        // defer-rescale (T13)
        if (__any(mx > m + 8.0f)) {
            float mn = fmaxf(m, mx);
            float sfv = __builtin_amdgcn_exp2f(m - mn);
            m = mn;
            l *= sfv;
            #pragma unroll
            for (int dt = 0; dt < 4; dt++)
                #pragma unroll
                for (int e = 0; e < 16; e++) aoT[dt][e] *= sfv;
        }

        // P = exp2(g - m); denom includes ALL entries; PV term zeroed where g==0
        float rs = 0.f;
        #pragma unroll
        for (int ni = 0; ni < 2; ni++)
            #pragma unroll
            for (int e = 0; e < 16; e++) {
                float g = sT[ni][e];
                float p = __builtin_amdgcn_exp2f(g - m);
                rs += p;
                sT[ni][e] = (g != 0.0f) ? p : 0.0f;
            }
        rs += __shfl_xor(rs, 32);
        l += rs;

        // pack P -> A-frags: 16 cvt_pk + 8 permlane32_swap (R4-verified)
        s16x8 pfrag[4];
        #pragma unroll
        for (int sp = 0; sp < 4; sp++) {
            const int ni = sp >> 1;
            const int ru = (2 * sp) & 3, rv2 = (2 * sp + 1) & 3;
            unsigned u0 = pk_bf16(sT[ni][ru * 4 + 0], sT[ni][ru * 4 + 1]);
            unsigned u1 = pk_bf16(sT[ni][ru * 4 + 2], sT[ni][ru * 4 + 3]);
            unsigned v0 = pk_bf16(sT[ni][rv2 * 4 + 0], sT[ni][rv2 * 4 + 1]);
            unsigned v1 = pk_bf16(sT[ni][rv2 * 4 + 2], sT[ni][rv2 * 4 + 3]);
            pl32_swap(u0, v0);
            pl32_swap(u1, v1);
            u32x4 w = {u0, u1, v0, v1};
            pfrag[sp] = __builtin_bit_cast(s16x8, w);
        }

        // O^T += V^T · P^T
        __builtin_amdgcn_s_setprio(1);
        #pragma unroll
        for (int dt = 0; dt < 4; dt++)
            #pragma unroll
            for (int sp = 0; sp < 4; sp++) {
                int r = dt * 32 + lq;
                int slot = (2 * sp + hl) ^ mVl;
                s16x8 vf = *(const s16x8*)(&vt[cur][r * 64 + slot * 8]);
                aoT[dt] = __builtin_amdgcn_mfma_f32_32x32x16_bf16(vf, pfrag[sp], aoT[dt], 0, 0, 0);
            }
        __builtin_amdgcn_s_setprio(0);
        __syncthreads();   // all reads of buf[cur] done; next-tile gl_lds drained
    }

    // normalize and write x[b, n=q, hh*HD + d]; d = (reg&3) + 8*(reg>>2) + 4*hl + 32*dt
    float inv = 1.0f / l;
    u16* orow = xout + ((size_t)(b * N_ + q)) * DIM_ + hh * HD_;
    #pragma unroll
    for (int dt = 0; dt < 4; dt++)
        #pragma unroll
        for (int r2 = 0; r2 < 4; r2++) {
            u16x4 ov;
            #pragma unroll
            for (int e = 0; e < 4; e++)
                ov[e] = f2bf(aoT[dt][r2 * 4 + e] * inv);
            *(u16x4*)(orow + dt * 32 + r2 * 8 + hl * 4) = ov;
        }
}

// ---------------------------------------------------------------- R3 fallback attention
// (used only if ws_size can't hold transT; proven at 155.7 us)
__global__ __launch_bounds__(512) void attn_fb(const u16* __restrict__ Qh,
                                               const u16* __restrict__ Kh,
                                               const u16* __restrict__ Vt,
                                               const float* __restrict__ trans,
                                               u16* __restrict__ xout) {
    __shared__ __align__(16) u16 kt[64 * 128];
    __shared__ __align__(16) u16 vt[128 * 64];
    __shared__ __align__(16) u16 plds[8][16 * 72];

    const int tid = threadIdx.x, lane = tid & 63, wave = tid >> 6;
    const int qt = blockIdx.x, h = blockIdx.y, b = blockIdx.z;
    const int qrow_base = qt * 128 + wave * 16;

    const u16* Qbh = Qh + (size_t)(b * H_ + h) * N_ * HD_;
    const u16* Kbh = Kh + (size_t)(b * H_ + h) * N_ * HD_;
    const u16* Vbh = Vt + (size_t)(b * H_ + h) * HD_ * N_;
    const float* trow = trans + (size_t)b * N_ * N_
                      + (size_t)(qrow_base + ((lane >> 4) << 2)) * N_ + (lane & 15);

    s16x8 qf[4];
    {
        int r = qrow_base + (lane & 15);
        #pragma unroll
        for (int kd = 0; kd < 4; kd++)
            qf[kd] = *(const s16x8*)(Qbh + (size_t)r * HD_ + kd * 32 + ((lane >> 4) << 3));
    }
    auto stageKV = [&](int kv0) {
        int rbk = wave * 8, rbv = wave * 16;
        #pragma unroll
        for (int j = 0; j < 2; j++) {
            int c = j * 64 + lane;
            int rk = rbk + (c >> 4), ck = (c & 15) ^ (rk & 15);
            gl_lds16(Kbh + (size_t)(kv0 + rk) * HD_ + ck * 8, kt + rbk * 128 + j * 512);
            int rv = rbv + (c >> 3), cv = (c & 7) ^ (rv & 7);
            gl_lds16(Vbh + (size_t)rv * N_ + kv0 + cv * 8, vt + rbv * 64 + j * 512);
        }
    };

    float m[4], l[4];
    #pragma unroll
    for (int r = 0; r < 4; r++) { m[r] = -3.0e38f; l[r] = 0.f; }
    f32x4 ao[8] = {};

    for (int kv0 = 0; kv0 < N_; kv0 += 64) {
        stageKV(kv0);
        __syncthreads();
        f32x4 s[4] = {};
        #pragma unroll
        for (int kd = 0; kd < 4; kd++)
            #pragma unroll
            for (int ni = 0; ni < 4; ni++) {
                int r = ni * 16 + (lane & 15);
                int sc = (kd * 4 + (lane >> 4)) ^ (lane & 15);
                s16x8 bfr = *(const s16x8*)(&kt[r * 128 + sc * 8]);
                s[ni] = __builtin_amdgcn_mfma_f32_16x16x32_bf16(qf[kd], bfr, s[ni], 0, 0, 0);
            }
        float pmax[4] = {-3.0e38f, -3.0e38f, -3.0e38f, -3.0e38f};
        #pragma unroll
        for (int ni = 0; ni < 4; ni++)
            #pragma unroll
            for (int r = 0; r < 4; r++) {
                float tt = trow[(size_t)r * N_ + kv0 + ni * 16];
                float gg = s[ni][r] * tt;
                s[ni][r] = gg;
                pmax[r] = fmaxf(pmax[r], gg);
            }
        #pragma unroll
        for (int r = 0; r < 4; r++) {
            float p = pmax[r];
            p = fmaxf(p, __shfl_xor(p, 1));
            p = fmaxf(p, __shfl_xor(p, 2));
            p = fmaxf(p, __shfl_xor(p, 4));
            p = fmaxf(p, __shfl_xor(p, 8));
            pmax[r] = p;
        }
        bool need = false;
        #pragma unroll
        for (int r = 0; r < 4; r++) need = need || (pmax[r] > m[r] + 8.0f);
        if (__any(need)) {
            #pragma unroll
            for (int r = 0; r < 4; r++) {
                float mn = fmaxf(m[r], pmax[r]);
                float sfv = __builtin_amdgcn_exp2f(m[r] - mn);
                m[r] = mn; l[r] *= sfv;
                #pragma unroll
                for (int t = 0; t < 8; t++) ao[t][r] *= sfv;
            }
        }
        float rowsum[4] = {0.f, 0.f, 0.f, 0.f};
        u16* pw = &plds[wave][0];
        #pragma unroll
        for (int ni = 0; ni < 4; ni++)
            #pragma unroll
            for (int r = 0; r < 4; r++) {
                float gg = s[ni][r];
                float e = __builtin_amdgcn_exp2f(gg - m[r]);
                rowsum[r] += e;
                float pe = (gg != 0.0f) ? e : 0.0f;
                pw[(((lane >> 4) << 2) + r) * 72 + ni * 16 + (lane & 15)] = f2bf(pe);
            }
        #pragma unroll
        for (int r = 0; r < 4; r++) {
            float ssum = rowsum[r];
            ssum += __shfl_xor(ssum, 1);
            ssum += __shfl_xor(ssum, 2);
            ssum += __shfl_xor(ssum, 4);
            ssum += __shfl_xor(ssum, 8);
            l[r] += ssum;
        }
        #pragma unroll
        for (int kk = 0; kk < 2; kk++) {
            s16x8 pa = *(const s16x8*)(&pw[(lane & 15) * 72 + kk * 32 + ((lane >> 4) << 3)]);
            #pragma unroll
            for (int t = 0; t < 8; t++) {
                int r = t * 16 + (lane & 15);
                int sc = (kk * 4 + (lane >> 4)) ^ (r & 7);
                s16x8 vb = *(const s16x8*)(&vt[r * 64 + sc * 8]);
                ao[t] = __builtin_amdgcn_mfma_f32_16x16x32_bf16(pa, vb, ao[t], 0, 0, 0);
            }
        }
        __syncthreads();
    }
    #pragma unroll
    for (int r = 0; r < 4; r++) {
        float inv = 1.0f / l[r];
        int n = qrow_base + ((lane >> 4) << 2) + r;
        u16* orow = xout + ((size_t)(b * N_ + n)) * DIM_ + h * HD_;
        #pragma unroll
        for (int t = 0; t < 8; t++)
            orow[t * 16 + (lane & 15)] = f2bf(ao[t][r] * inv);
    }
}

// ---------------------------------------------------------------- launch
extern "C" void kernel_launch(void* const* d_in, const int* in_sizes, int n_in,
                              void* d_out, int out_size, void* d_ws, size_t ws_size,
                              hipStream_t stream) {
    const float* q     = (const float*)d_in[0];
    const float* k     = (const float*)d_in[1];
    const float* v     = (const float*)d_in[2];
    const float* trans = (const float*)d_in[3];
    const float* Wq    = (const float*)d_in[4];
    const float* Wk    = (const float*)d_in[5];
    const float* Wv    = (const float*)d_in[6];
    const float* Wp    = (const float*)d_in[7];
    const float* bp    = (const float*)d_in[8];

    // workspace map (big path, 136 MiB):
    //  [0,16M): xb attention output bf16
    //  [16M..24M): Wq,Wk,Wv,Wp bf16 ; [24..40M): Qh ; [40..56M): Kh ; [56..72M): Vt
    //  [72M..120M): qb/kb/vb bf16 (dead after projections)
    //  [72M..136M): transT (written after qb/kb/vb are dead)
    char* ws = (char*)d_ws;
    u16* xb  = (u16*)(ws);
    u16* wqb = (u16*)(ws + (16u << 20));
    u16* wkb = (u16*)(ws + (18u << 20));
    u16* wvb = (u16*)(ws + (20u << 20));
    u16* wpb = (u16*)(ws + (22u << 20));
    u16* QhB = (u16*)(ws + (24u << 20));
    u16* KhB = (u16*)(ws + (40u << 20));
    u16* VtB = (u16*)(ws + (56u << 20));
    u16* qb  = (u16*)(ws + (72u << 20));
    u16* kb  = (u16*)(ws + (88u << 20));
    u16* vb  = (u16*)(ws + (104u << 20));
    float* tT = (float*)(ws + (72u << 20));
    const bool big = ws_size >= (136ull << 20);

    dim3 blk(256);
    cvt_w4<<<dim3(512, 4), blk, 0, stream>>>(Wq, Wk, Wv, Wp, wqb);

    dim3 pg(DIM_ / 128, MTOK / 128);   // (8, 64)

    if (big) {
        cvt3<<<dim3(4096, 3), blk, 0, stream>>>(q, k, v, qb, kb, vb);
        gemm_bt<0><<<pg, blk, 0, stream>>>(qb, wqb, QhB, nullptr, QSCALE_, MTOK, DIM_, DIM_);
        gemm_bt<0><<<pg, blk, 0, stream>>>(kb, wkb, KhB, nullptr, 1.0f, MTOK, DIM_, DIM_);
        gemm_bt<1><<<pg, blk, 0, stream>>>(vb, wvb, VtB, nullptr, 1.0f, MTOK, DIM_, DIM_);
        transpose_f32<<<dim3(N_ / 64, N_ / 64, B_), blk, 0, stream>>>(trans, tT);
        attn_swapped<<<dim3(16, 8, 4), dim3(256), 0, stream>>>(QhB, KhB, VtB, tT, xb);
    } else {
        u16* tmp = xb;   // serial staging, reused as x afterwards
        cvt_f32_bf16<<<dim3(8192), blk, 0, stream>>>(q, tmp, MTOK * DIM_);
        gemm_bt<0><<<pg, blk, 0, stream>>>(tmp, wqb, QhB, nullptr, QSCALE_, MTOK, DIM_, DIM_);
        cvt_f32_bf16<<<dim3(8192), blk, 0, stream>>>(k, tmp, MTOK * DIM_);
        gemm_bt<0><<<pg, blk, 0, stream>>>(tmp, wkb, KhB, nullptr, 1.0f, MTOK, DIM_, DIM_);
        cvt_f32_bf16<<<dim3(8192), blk, 0, stream>>>(v, tmp, MTOK * DIM_);
        gemm_bt<1><<<pg, blk, 0, stream>>>(tmp, wvb, VtB, nullptr, 1.0f, MTOK, DIM_, DIM_);
        attn_fb<<<dim3(N_ / 128, H_, B_), dim3(512), 0, stream>>>(QhB, KhB, VtB, trans, xb);
    }

    gemm_bt<2><<<pg, blk, 0, stream>>>(xb, wpb, d_out, bp, 1.0f, MTOK, DIM_, DIM_);
}